// Round 12
// baseline (184.999 us; speedup 1.0000x reference)
//
#include <hip/hip_runtime.h>

// Fused causal self-attention block, MI355X gfx950.
// B=2, T=2048, E=1024, H=16, D=64.  All MFMA in bf16 (mfma_f32_16x16x32_bf16),
// fp32 accumulation. Verified fragment layouts (learn_hip m89/m91):
//   A[m = lane&15][k = (lane>>4)*8 + j]   (8 bf16 = 16B contiguous)
//   B[k = (lane>>4)*8 + j][n = lane&15]
//   C/D[row = (lane>>4)*4 + r][col = lane&15]
// GEMMs (R11): dbuf XOR-swizzled LDS, 1 barrier/K-step (qkv 63 -> ~40us).
// Attention (R9/R10): block LDS staging + XOR swizzle (101 -> 43us).
// R12: attn block supply. R11 ran 512 four-wave blocks = exactly 2/CU;
// barrier-paced loop + 17..32-iter imbalance left stalls uncovered (MfmaUtil
// 15%, occ 16%). Now 1024 two-wave blocks (32/head): waves w=0,1 take tiles
// 2t+w (shared ktmax=t>>1, uniform loop), LDS ~41KB -> 3 blocks/CU resident,
// 4/CU supply. Staged K/V doubles (~540MB via L2, ~15TB/s << 34.5 ceiling).

typedef unsigned short u16;
typedef __bf16 bf8 __attribute__((ext_vector_type(8)));
typedef float f32x4 __attribute__((ext_vector_type(4)));

struct __align__(8) u16x4s { u16 v[4]; };

__device__ __forceinline__ u16 f2b(float f) {
    union { float f; unsigned u; } x{f};
    unsigned r = x.u + 0x7fffu + ((x.u >> 16) & 1u);   // RNE
    return (u16)(r >> 16);
}

__device__ __forceinline__ f32x4 mfma16(bf8 a, bf8 b, f32x4 c) {
    return __builtin_amdgcn_mfma_f32_16x16x32_bf16(a, b, c, 0, 0, 0);
}

__device__ __forceinline__ float fexp2(float x) {
    return __builtin_amdgcn_exp2f(x);                  // v_exp_f32
}

// async global->LDS, 16B per lane. LDS dest must be wave-uniform base + lane*16.
__device__ __forceinline__ void gload_lds16(const u16* g, u16* l) {
    __builtin_amdgcn_global_load_lds(
        (__attribute__((address_space(1))) void*)(g),
        (__attribute__((address_space(3))) void*)(l), 16, 0, 0);
}

// ---------------- prep: x->bf16 convert + both weight transposes ----------------
// blocks [0,4096): cvt; [4096,4864): W_attn tr (16x48); [4864,5120): W_proj tr.
__global__ __launch_bounds__(256) void k_prep(const float* __restrict__ x,
                                              const float* __restrict__ Wa,
                                              const float* __restrict__ Wp,
                                              u16* __restrict__ Xb,
                                              u16* __restrict__ WtA,
                                              u16* __restrict__ WtP) {
    __shared__ float tile[64][65];
    int id = blockIdx.x, t = threadIdx.x;
    if (id < 4096) {                         // convert 4 floats/thread
        int i = id * 256 + t;
        float4 v = ((const float4*)x)[i];
        ushort4 o;
        o.x = f2b(v.x); o.y = f2b(v.y); o.z = f2b(v.z); o.w = f2b(v.w);
        ((ushort4*)Xb)[i] = o;
        return;
    }
    const float* in; u16* out; int N, j;
    if (id < 4864) { j = id - 4096; in = Wa; out = WtA; N = 3072; }
    else           { j = id - 4864; in = Wp; out = WtP; N = 1024; }
    int k0 = (j & 15) * 64, n0 = (j >> 4) * 64;
    int c = t & 63, r0 = t >> 6;
#pragma unroll
    for (int i = 0; i < 16; ++i) {
        int r = r0 + i * 4;
        tile[r][c] = in[(size_t)(k0 + r) * N + n0 + c];
    }
    __syncthreads();
#pragma unroll
    for (int i = 0; i < 16; ++i) {
        int r = r0 + i * 4;
        out[(size_t)(n0 + r) * 1024 + k0 + c] = f2b(tile[c][r]);
    }
}

// =====================================================================
// GEMM core v2: C[128x128]/block, A[M][1024] @ Wt[N][1024]^T.
// Double-buffered XOR-swizzled LDS, 1 barrier per K-step (32 steps).
// =====================================================================
#define GEMM_STAGE(GA0, GA1, GB0, GB1, K, B)                                   \
    do {                                                                       \
        gload_lds16(GA0 + (K), As[B] + tid * 8);                               \
        gload_lds16(GA1 + (K), As[B] + (256 + tid) * 8);                       \
        gload_lds16(GB0 + (K), Bs[B] + tid * 8);                               \
        gload_lds16(GB1 + (K), Bs[B] + (256 + tid) * 8);                       \
    } while (0)

#define GEMM_CORE(Aptr, Bptr)                                                  \
    int tid = threadIdx.x;                                                     \
    int w = tid >> 6, lane = tid & 63, l16 = lane & 15, quad = lane >> 4;      \
    int m0 = blockIdx.x * 128, n0 = blockIdx.y * 128;                          \
    int wr = (w >> 1) * 64, wc = (w & 1) * 64;                                 \
    __shared__ u16 As[2][128 * 32];                                            \
    __shared__ u16 Bs[2][128 * 32];                                            \
    f32x4 acc[4][4];                                                           \
    _Pragma("unroll") for (int mi = 0; mi < 4; ++mi)                           \
        _Pragma("unroll") for (int ni = 0; ni < 4; ++ni)                       \
            _Pragma("unroll") for (int r = 0; r < 4; ++r) acc[mi][ni][r] = 0.f;\
    int srow0 = tid >> 2, srow1 = 64 + srow0;                                  \
    int slc = ((tid & 3) ^ ((tid >> 3) & 3)) * 8;   /* swizzled src chunk */   \
    const u16* gA0 = Aptr + (size_t)(m0 + srow0) * 1024 + slc;                 \
    const u16* gA1 = Aptr + (size_t)(m0 + srow1) * 1024 + slc;                 \
    const u16* gB0 = Bptr + (size_t)(n0 + srow0) * 1024 + slc;                 \
    const u16* gB1 = Bptr + (size_t)(n0 + srow1) * 1024 + slc;                 \
    int cq = (quad ^ ((l16 >> 1) & 3)) * 8;         /* frag phys chunk */      \
    GEMM_STAGE(gA0, gA1, gB0, gB1, 0, 0);                                      \
    for (int it = 0; it < 32; ++it) {                                          \
        int pb = it & 1;                                                       \
        __syncthreads();                  /* drains buf[pb] staging */         \
        bf8 af[4], bf[4];                                                      \
        _Pragma("unroll") for (int mi = 0; mi < 4; ++mi)                       \
            af[mi] = *(const bf8*)(As[pb] + (wr + mi * 16 + l16) * 32 + cq);   \
        _Pragma("unroll") for (int ni = 0; ni < 4; ++ni)                       \
            bf[ni] = *(const bf8*)(Bs[pb] + (wc + ni * 16 + l16) * 32 + cq);   \
        if (it < 31) GEMM_STAGE(gA0, gA1, gB0, gB1, (it + 1) * 32, pb ^ 1);    \
        _Pragma("unroll") for (int mi = 0; mi < 4; ++mi)                       \
            _Pragma("unroll") for (int ni = 0; ni < 4; ++ni)                   \
                acc[mi][ni] = mfma16(af[mi], bf[ni], acc[mi][ni]);             \
    }

// ---------------- QKV GEMM: [4096,1024] @ Wt[3072,1024] + bias ----------------
// epilogue: Q (pre-scaled by 0.125*log2e) and K into [B*H][T][D];
//           V TILED-TRANSPOSED into [B*H][32][64 d][64 t] (8KB tiles).
__global__ __launch_bounds__(256, 3) void k_qkv(const u16* __restrict__ Xb,
                                                const u16* __restrict__ WtA,
                                                const float* __restrict__ ba,
                                                u16* __restrict__ Qb,
                                                u16* __restrict__ Kb,
                                                u16* __restrict__ Vtb) {
    GEMM_CORE(Xb, WtA)
    int sel = n0 >> 10;                       // 0:Q 1:K 2:V (uniform per block)
    u16* dst = sel == 0 ? Qb : (sel == 1 ? Kb : Vtb);
    const float qs = 0.18033688011112042f;    // 0.125 * log2(e)
#pragma unroll
    for (int ni = 0; ni < 4; ++ni) {
        int n = n0 + wc + ni * 16 + l16;
        float bias = ba[n];
        int h = (n & 1023) >> 6;
        int d = n & 63;
#pragma unroll
        for (int mi = 0; mi < 4; ++mi)
#pragma unroll
            for (int r = 0; r < 4; ++r) {
                int m = m0 + wr + mi * 16 + quad * 4 + r;
                int bb = m >> 11, tt = m & 2047;
                float v = acc[mi][ni][r] + bias;
                size_t hb = (size_t)(bb * 16 + h);
                if (sel == 2)                             // V^T tiled
                    dst[hb * 131072 + (size_t)(tt >> 6) * 4096 + d * 64 + (tt & 63)] = f2b(v);
                else
                    dst[(hb * 2048 + tt) * 64 + d] =
                        f2b(sel == 0 ? v * qs : v);
            }
    }
}

// ---------------- proj GEMM: AO[4096,1024] @ WtP[1024,1024] + bias -> fp32 ----------------
__global__ __launch_bounds__(256, 3) void k_proj(const u16* __restrict__ AO,
                                                 const u16* __restrict__ WtP,
                                                 const float* __restrict__ bp,
                                                 float* __restrict__ out) {
    GEMM_CORE(AO, WtP)
#pragma unroll
    for (int ni = 0; ni < 4; ++ni) {
        int n = n0 + wc + ni * 16 + l16;
        float bias = bp[n];
#pragma unroll
        for (int mi = 0; mi < 4; ++mi)
#pragma unroll
            for (int r = 0; r < 4; ++r) {
                int m = m0 + wr + mi * 16 + quad * 4 + r;
                out[(size_t)m * 1024 + n] = acc[mi][ni][r] + bias;
            }
    }
}

// ---------------- flash attention (causal) ----------------
// Block = 2 waves (128 thr); wave w handles q-tiles aA=2t+w and aB=aA+64
// (same head); both waves share ktmaxA = t>>1 (uniform loop; barriers legal).
// K/V staged to LDS via global_load_lds, double-buffered, 1 barrier/iter.
// LDS images XOR-swizzled at 16B chunks: K rows by (row>>2)&7, V by row&7.

// stage swizzled K tile ([key][d]) and V^T tile ([d][key]) into buf B.
// 512 16B-chunks each; 128 threads x 4 chunks. lc = pc ^ s(row).
#define STAGE(KT, B) do {                                                     \
    const u16* kt_ = Kh + (size_t)(KT) * 4096;                                \
    const u16* vt_ = Vh + (size_t)(KT) * 4096;                                \
    _Pragma("unroll") for (int j_ = 0; j_ < 4; ++j_) {                        \
        int ci_ = tid + 128 * j_;                                             \
        gload_lds16(kt_ + (ci_ >> 3) * 64 +                                   \
                    (((ci_ & 7) ^ ((ci_ >> 5) & 7)) * 8), Ks[B] + ci_ * 8);   \
        gload_lds16(vt_ + (ci_ >> 3) * 64 +                                   \
                    (((ci_ & 7) ^ ((ci_ >> 3) & 7)) * 8), Vs[B] + ci_ * 8);   \
    }                                                                         \
} while (0)

// QK + softmax for one q-tile into its P buffer (no fence here)
#define QK_SOFT(KT, KF, QF0, QF1, LI, QROW, KTM, PBUF) do {                   \
    int kb_ = (KT) * 64;                                                      \
    bool diag_ = ((KT) == (KTM));                                             \
    f32x4 s_acc[4];                                                           \
    _Pragma("unroll") for (int s = 0; s < 4; ++s)                             \
        _Pragma("unroll") for (int r = 0; r < 4; ++r) s_acc[s][r] = 0.f;      \
    _Pragma("unroll") for (int sub = 0; sub < 4; ++sub) {                     \
        s_acc[sub] = mfma16(QF0, KF[sub][0], s_acc[sub]);                     \
        s_acc[sub] = mfma16(QF1, KF[sub][1], s_acc[sub]);                     \
    }                                                                         \
    _Pragma("unroll") for (int r = 0; r < 4; ++r) {                           \
        float p[4];                                                           \
        if (diag_) {                                                          \
            int qg_ = (QROW) + quad * 4 + r;                                  \
            _Pragma("unroll") for (int sub = 0; sub < 4; ++sub) {             \
                int key_ = kb_ + 4 * l16 + sub;                               \
                p[sub] = fexp2(key_ <= qg_ ? s_acc[sub][r] : -1e30f);         \
            }                                                                 \
        } else {                                                              \
            _Pragma("unroll") for (int sub = 0; sub < 4; ++sub)               \
                p[sub] = fexp2(s_acc[sub][r]);                                \
        }                                                                     \
        LI[r] += (p[0] + p[1]) + (p[2] + p[3]);                               \
        u16x4s pk_;                                                           \
        _Pragma("unroll") for (int sub = 0; sub < 4; ++sub)                   \
            pk_.v[sub] = f2b(p[sub]);                                         \
        *(u16x4s*)&PBUF[quad * 4 + r][l16 * 4] = pk_;   /* ds_write_b64 */    \
    }                                                                         \
} while (0)

#define PV_ACC(VF, PBUF, OACC) do {                                           \
    bf8 pf0 = *(const bf8*)&PBUF[l16][quad * 8];                              \
    bf8 pf1 = *(const bf8*)&PBUF[l16][32 + quad * 8];                         \
    _Pragma("unroll") for (int dt = 0; dt < 4; ++dt) {                        \
        OACC[dt] = mfma16(pf0, VF[dt][0], OACC[dt]);                          \
        OACC[dt] = mfma16(pf1, VF[dt][1], OACC[dt]);                          \
    }                                                                         \
} while (0)

__global__ __launch_bounds__(128, 2) void k_attn(const u16* __restrict__ Qb,
                                                 const u16* __restrict__ Kb,
                                                 const u16* __restrict__ Vtb,
                                                 u16* __restrict__ AO) {
    // XCD-affinity swizzle: 32 blocks/head share id%8 (same XCD). Longest first.
    int id = blockIdx.x;                     // 0..1023
    int bh = (id & 7) * 4 + ((id >> 3) & 3);
    int t  = 31 - (id >> 5);                 // 0..31
    int tid = threadIdx.x;
    int w = tid >> 6, lane = tid & 63, l16 = lane & 15, quad = lane >> 4;

    const u16* Qh = Qb  + (size_t)bh * 2048 * 64;
    const u16* Kh = Kb  + (size_t)bh * 2048 * 64;
    const u16* Vh = Vtb + (size_t)bh * 131072;      // V^T tiled: [kt][d][t64]

    int qrA = (2 * t + w) * 16;              // wave w -> q-tile 2t+w
    int qrB = qrA + 1024;
    int ktmaxA = t >> 1, ktmaxB = (t >> 1) + 16;    // uniform across waves

    __shared__ u16 Ks[2][64 * 64];           // swizzled [key][d] image, 8KB each
    __shared__ u16 Vs[2][64 * 64];           // swizzled [d][key] image
    __shared__ u16 P[2][2][16][72];          // per-wave, per-tile (pad 72)

    bf8 qfA0 = *(const bf8*)(Qh + (size_t)(qrA + l16) * 64 + quad * 8);
    bf8 qfA1 = *(const bf8*)(Qh + (size_t)(qrA + l16) * 64 + 32 + quad * 8);
    bf8 qfB0 = *(const bf8*)(Qh + (size_t)(qrB + l16) * 64 + quad * 8);
    bf8 qfB1 = *(const bf8*)(Qh + (size_t)(qrB + l16) * 64 + 32 + quad * 8);

    float l_iA[4] = {0.f, 0.f, 0.f, 0.f};
    float l_iB[4] = {0.f, 0.f, 0.f, 0.f};
    f32x4 o_accA[4], o_accB[4];
#pragma unroll
    for (int dt = 0; dt < 4; ++dt)
#pragma unroll
        for (int r = 0; r < 4; ++r) { o_accA[dt][r] = 0.f; o_accB[dt][r] = 0.f; }

    int xsw = (l16 & 7) * 8;                 // read-side XOR term, u16 units

    STAGE(0, 0);
    for (int kt = 0; kt <= ktmaxB; ++kt) {
        int pb = kt & 1;
        __syncthreads();   // drains buf[pb] staging; fences buf reuse

        // K/V fragments from swizzled LDS (physical chunk = logical ^ (l16&7))
        bf8 kf[4][2], vf[4][2];
        const u16* kb_ = Ks[pb];
        const u16* vb_ = Vs[pb];
#pragma unroll
        for (int sub = 0; sub < 4; ++sub)
#pragma unroll
            for (int ks = 0; ks < 2; ++ks)
                kf[sub][ks] = *(const bf8*)(kb_ + (4 * l16 + sub) * 64 +
                                            (((ks * 32 + quad * 8)) ^ xsw));
#pragma unroll
        for (int dt = 0; dt < 4; ++dt)
#pragma unroll
            for (int ks = 0; ks < 2; ++ks)
                vf[dt][ks] = *(const bf8*)(vb_ + (dt * 16 + l16) * 64 +
                                           (((ks * 32 + quad * 8)) ^ xsw));

        if (kt < ktmaxB) STAGE(kt + 1, pb ^ 1);   // async, flies during compute

        bool aAct = (kt <= ktmaxA);
        if (aAct) QK_SOFT(kt, kf, qfA0, qfA1, l_iA, qrA, ktmaxA, P[w][0]);
        QK_SOFT(kt, kf, qfB0, qfB1, l_iB, qrB, ktmaxB, P[w][1]);
        asm volatile("s_waitcnt lgkmcnt(0)" ::: "memory");  // P write->read
        if (aAct) PV_ACC(vf, P[w][0], o_accA);
        PV_ACC(vf, P[w][1], o_accB);
    }

    // reduce l across the 16 lanes sharing each row
    float linvA[4], linvB[4];
#pragma unroll
    for (int r = 0; r < 4; ++r) {
        float la = l_iA[r], lb = l_iB[r];
        la += __shfl_xor(la, 1, 64); lb += __shfl_xor(lb, 1, 64);
        la += __shfl_xor(la, 2, 64); lb += __shfl_xor(lb, 2, 64);
        la += __shfl_xor(la, 4, 64); lb += __shfl_xor(lb, 4, 64);
        la += __shfl_xor(la, 8, 64); lb += __shfl_xor(lb, 8, 64);
        linvA[r] = __builtin_amdgcn_rcpf(la);
        linvB[r] = __builtin_amdgcn_rcpf(lb);
    }

    // epilogue: AO[b*2048+q][h*64+d] bf16  (proj-GEMM A layout)
    int b = bh >> 4, h = bh & 15;
#pragma unroll
    for (int dt = 0; dt < 4; ++dt)
#pragma unroll
        for (int r = 0; r < 4; ++r) {
            int off = quad * 4 + r;
            size_t rowA = (size_t)b * 2048 + qrA + off;
            size_t rowB = (size_t)b * 2048 + qrB + off;
            AO[rowA * 1024 + h * 64 + dt * 16 + l16] = f2b(o_accA[dt][r] * linvA[r]);
            AO[rowB * 1024 + h * 64 + dt * 16 + l16] = f2b(o_accB[dt][r] * linvB[r]);
        }
}

extern "C" void kernel_launch(void* const* d_in, const int* in_sizes, int n_in,
                              void* d_out, int out_size, void* d_ws, size_t ws_size,
                              hipStream_t stream) {
    const float* x  = (const float*)d_in[0];
    const float* Wa = (const float*)d_in[1];
    const float* ba = (const float*)d_in[2];
    const float* Wp = (const float*)d_in[3];
    const float* bp = (const float*)d_in[4];
    float* out = (float*)d_out;

    char* ws = (char*)d_ws;
    const size_t MB = 1024 * 1024;
    u16* Xb  = (u16*)(ws);             // 8 MB  x as bf16   (reused as AO later)
    u16* WtA = (u16*)(ws + 8  * MB);   // 6 MB  W_attn^T bf16
    u16* WtP = (u16*)(ws + 14 * MB);   // 2 MB  W_proj^T bf16
    u16* Qb  = (u16*)(ws + 16 * MB);   // 8 MB  [B*H][T][D], pre-scaled
    u16* Kb  = (u16*)(ws + 24 * MB);   // 8 MB  [B*H][T][D]
    u16* Vtb = (u16*)(ws + 32 * MB);   // 8 MB  [B*H][32][64][64] tiled V^T
    u16* AO  = Xb;                     // alias: Xb dead after k_qkv (stream-ordered)

    k_prep<<<dim3(5120),    dim3(256), 0, stream>>>(x, Wa, Wp, Xb, WtA, WtP);
    k_qkv <<<dim3(32, 24),  dim3(256), 0, stream>>>(Xb, WtA, ba, Qb, Kb, Vtb);
    k_attn<<<dim3(1024),    dim3(128), 0, stream>>>(Qb, Kb, Vtb, AO);
    k_proj<<<dim3(32, 8),   dim3(256), 0, stream>>>(AO, WtP, bp, out);
}